// Round 1
// baseline (19360.199 us; speedup 1.0000x reference)
//
#include <hip/hip_runtime.h>
#include <hip/hip_cooperative_groups.h>

#define VOCAB 25000
#define EDIM  300
#define EPAD  320
#define HDIM  512
#define G4    2048
#define BATCH 128
#define TLEN  512

typedef __attribute__((ext_vector_type(8))) short short8;
typedef __attribute__((ext_vector_type(4))) float f32x4;

static __device__ __forceinline__ unsigned short f2bf(float f) {
    unsigned int u = __float_as_uint(f);
    unsigned int r = u + 0x7fffu + ((u >> 16) & 1u);   // round-to-nearest-even
    return (unsigned short)(r >> 16);
}

// Convert f32 [rows x cs] -> bf16 [rows x cd], zero-padding cols cs..cd.
__global__ void conv_pad(const float* __restrict__ src, unsigned short* __restrict__ dst,
                         int rows, int cs, int cd) {
    long total = (long)rows * cd;
    for (long i = blockIdx.x * (long)blockDim.x + threadIdx.x; i < total;
         i += (long)gridDim.x * blockDim.x) {
        int r = (int)(i / cd), c = (int)(i % cd);
        dst[i] = (c < cs) ? f2bf(src[(long)r * cs + c]) : (unsigned short)0;
    }
}

// Persistent cooperative LSTM. 64 blocks x 1024 threads.
// block = (batch-tile of 16 rows) x (j-tile of 64 h-cols); wave (of 16) = (gate, jsub16).
// Per step: gates = emb[x[:,t]] @ Wih^T + h @ Whh^T (both via 16x16x32 bf16 MFMA,
// fragments loaded directly from row-major bf16 global), then pointwise LSTM update.
// c,h state lives in registers; h published per step as bf16 (double-buffered).
__global__ __launch_bounds__(1024, 1) void lstm_coop(
    const int* __restrict__ x, const float* __restrict__ h0, const float* __restrict__ c0,
    const float* __restrict__ b_ih, const float* __restrict__ b_hh,
    const unsigned short* __restrict__ embb, const unsigned short* __restrict__ wihb,
    const unsigned short* __restrict__ whhb, unsigned short* __restrict__ hb,
    float* __restrict__ out) {
    cooperative_groups::grid_group grid = cooperative_groups::this_grid();
    const int tid  = threadIdx.x;
    const int bt   = blockIdx.x >> 3;   // 0..7 batch tile
    const int jt   = blockIdx.x & 7;    // 0..7 j tile (64 wide)
    const int wave = tid >> 6, lane = tid & 63;
    const int gate = wave >> 2, jsub = wave & 3;
    const int m0   = bt * 16;
    const int g0   = gate * HDIM + jt * 64 + jsub * 16;

    // pointwise ownership: one (b, j) element per thread
    const int bl = tid >> 6;            // 0..15
    const int jl = tid & 63;            // 0..63
    const int bg = m0 + bl;
    const int jg = jt * 64 + jl;

    float c_reg = c0[bg * HDIM + jg];
    float h_reg = h0[bg * HDIM + jg];
    hb[bg * HDIM + jg] = f2bf(h_reg);   // init buffer 0

    float bsum[4];
#pragma unroll
    for (int g = 0; g < 4; ++g) bsum[g] = b_ih[g * HDIM + jg] + b_hh[g * HDIM + jg];

    __shared__ float lds_g[4][16][64];  // gate, b_local, j_local  (16 KiB)

    // MFMA fragment addressing (16x16x32 bf16): lane holds 8 contiguous k,
    // A row / B col = lane&15, k-chunk = (lane>>4)*8.
    const int arow = lane & 15;
    const int kch  = (lane >> 4) * 8;
    const int abatch = m0 + arow;
    const unsigned short* wih_base = wihb + (long)(g0 + arow) * EPAD + kch;
    const unsigned short* whh_base = whhb + (long)(g0 + arow) * HDIM + kch;

    __threadfence();

    for (int t = 0; t < TLEN; ++t) {
        grid.sync();
        const unsigned short* hread  = hb + (t & 1) * (BATCH * HDIM);
        unsigned short*       hwrite = hb + ((t + 1) & 1) * (BATCH * HDIM);

        f32x4 acc = {0.f, 0.f, 0.f, 0.f};
        // input projection: A = emb rows gathered per batch lane (K = 320, padded)
        const int tok = x[abatch * TLEN + t];
        const unsigned short* emb_base = embb + (long)tok * EPAD + kch;
#pragma unroll
        for (int kk = 0; kk < EPAD / 32; ++kk) {
            short8 a = *(const short8*)(emb_base + kk * 32);
            short8 b = *(const short8*)(wih_base + kk * 32);
            acc = __builtin_amdgcn_mfma_f32_16x16x32_bf16(a, b, acc, 0, 0, 0);
        }
        // recurrent projection: A = h (K = 512)
        const unsigned short* h_base = hread + abatch * HDIM + kch;
#pragma unroll
        for (int kk = 0; kk < HDIM / 32; ++kk) {
            short8 a = *(const short8*)(h_base + kk * 32);
            short8 b = *(const short8*)(whh_base + kk * 32);
            acc = __builtin_amdgcn_mfma_f32_16x16x32_bf16(a, b, acc, 0, 0, 0);
        }
        // D layout: col = lane&15, row = (lane>>4)*4 + reg
        const int crow = (lane >> 4) * 4;
        const int ccol = jsub * 16 + (lane & 15);
#pragma unroll
        for (int r = 0; r < 4; ++r) lds_g[gate][crow + r][ccol] = acc[r];
        __syncthreads();

        float gi = lds_g[0][bl][jl] + bsum[0];
        float gf = lds_g[1][bl][jl] + bsum[1];
        float gg = lds_g[2][bl][jl] + bsum[2];
        float go = lds_g[3][bl][jl] + bsum[3];
        float si = 1.f / (1.f + __expf(-gi));
        float sf = 1.f / (1.f + __expf(-gf));
        float tg = tanhf(gg);
        float so = 1.f / (1.f + __expf(-go));
        c_reg = sf * c_reg + si * tg;
        h_reg = so * tanhf(c_reg);
        hwrite[bg * HDIM + jg] = f2bf(h_reg);
        __threadfence();
    }

    // outputs: [ y(128) | h_out(128x512) | c_out(128x512) ]
    out[BATCH + bg * HDIM + jg] = h_reg;
    out[BATCH + BATCH * HDIM + bg * HDIM + jg] = c_reg;
}

// y[b] = dot(h[b,:], fc_w) + fc_b ; one wave per batch row
__global__ void fc_k(const float* __restrict__ h, const float* __restrict__ fcw,
                     const float* __restrict__ fcb, float* __restrict__ y) {
    int b = blockIdx.x * 4 + (threadIdx.x >> 6);
    int lane = threadIdx.x & 63;
    float s = 0.f;
#pragma unroll
    for (int j = lane; j < HDIM; j += 64) s += h[b * HDIM + j] * fcw[j];
#pragma unroll
    for (int off = 32; off; off >>= 1) s += __shfl_down(s, off, 64);
    if (lane == 0) y[b] = s + fcb[0];
}

extern "C" void kernel_launch(void* const* d_in, const int* in_sizes, int n_in,
                              void* d_out, int out_size, void* d_ws, size_t ws_size,
                              hipStream_t stream) {
    const int*   x   = (const int*)d_in[0];
    const float* h0  = (const float*)d_in[1];
    const float* c0  = (const float*)d_in[2];
    const float* emb = (const float*)d_in[3];
    const float* Wih = (const float*)d_in[4];
    const float* Whh = (const float*)d_in[5];
    const float* bih = (const float*)d_in[6];
    const float* bhh = (const float*)d_in[7];
    const float* fcw = (const float*)d_in[8];
    const float* fcb = (const float*)d_in[9];
    float* out = (float*)d_out;

    char* ws = (char*)d_ws;
    unsigned short* embb = (unsigned short*)(ws);              // 25000*320*2 = 16,000,000
    unsigned short* wihb = (unsigned short*)(ws + 16000000);   //  2048*320*2 =  1,310,720
    unsigned short* whhb = (unsigned short*)(ws + 17310720);   //  2048*512*2 =  2,097,152
    unsigned short* hb   = (unsigned short*)(ws + 19407872);   // 2*128*512*2 =    262,144
    // total ws use: 19,670,016 bytes

    conv_pad<<<2048, 256, 0, stream>>>(emb, embb, VOCAB, EDIM, EPAD);
    conv_pad<<<512, 256, 0, stream>>>(Wih, wihb, G4, EDIM, EPAD);
    conv_pad<<<512, 256, 0, stream>>>(Whh, whhb, G4, HDIM, HDIM);

    void* args[] = {(void*)&x, (void*)&h0, (void*)&c0, (void*)&bih, (void*)&bhh,
                    (void*)&embb, (void*)&wihb, (void*)&whhb, (void*)&hb, (void*)&out};
    hipLaunchCooperativeKernel((void*)lstm_coop, dim3(64), dim3(1024), args, 0, stream);

    fc_k<<<32, 256, 0, stream>>>(out + BATCH, fcw, fcb, out);
}

// Round 2
// 6086.919 us; speedup vs baseline: 3.1806x; 3.1806x over previous
//
#include <hip/hip_runtime.h>

#define VOCAB 25000
#define EDIM  300
#define EPAD  320
#define HDIM  512
#define G4    2048
#define BATCH 128
#define TLEN  512
#define NB_J  16    // j-tile blocks per batch group
#define JT_W  32    // j-tile width
#define NTHR  512

typedef __attribute__((ext_vector_type(8))) short short8;
typedef __attribute__((ext_vector_type(4))) float f32x4;

static __device__ __forceinline__ unsigned short f2bf(float f) {
    unsigned int u = __float_as_uint(f);
    unsigned int r = u + 0x7fffu + ((u >> 16) & 1u);   // round-to-nearest-even
    return (unsigned short)(r >> 16);
}

// Convert f32 [rows x cs] -> bf16 [rows x cd], zero-padding cols cs..cd.
__global__ void conv_pad(const float* __restrict__ src, unsigned short* __restrict__ dst,
                         int rows, int cs, int cd) {
    long total = (long)rows * cd;
    for (long i = blockIdx.x * (long)blockDim.x + threadIdx.x; i < total;
         i += (long)gridDim.x * blockDim.x) {
        int r = (int)(i / cd), c = (int)(i % cd);
        dst[i] = (c < cs) ? f2bf(src[(long)r * cs + c]) : (unsigned short)0;
    }
}

// Persistent LSTM. 128 blocks x 512 threads. block = (bt: 16 batch rows) x (jt: 32 h-cols).
// Wave (8/block) = (gate, jsub16): one 16x16 MFMA tile, K = 320(emb) + 512(h).
// W_ih/W_hh fragments live in VGPRs for all 512 steps. Sync: per-batch-group (16 blocks)
// arrival counter + double-buffered h (bf16) in global.
__global__ __launch_bounds__(NTHR, 2) void lstm_pers(
    const int* __restrict__ x, const float* __restrict__ h0, const float* __restrict__ c0,
    const float* __restrict__ b_ih, const float* __restrict__ b_hh,
    const unsigned short* __restrict__ embb, const unsigned short* __restrict__ wihb,
    const unsigned short* __restrict__ whhb, unsigned short* __restrict__ hb,
    unsigned int* __restrict__ cnt, float* __restrict__ out) {
    const int tid  = threadIdx.x;
    const int bt   = blockIdx.x >> 4;   // 0..7 batch group
    const int jt   = blockIdx.x & 15;   // 0..15 j tile (32 wide)
    const int m0   = bt * 16;
    const int lane = tid & 63;
    const int wv   = tid >> 6;          // 0..7
    const int gate = wv >> 1, jsub = wv & 1;
    const int g0   = gate * HDIM + jt * JT_W + jsub * 16;
    const int arow = lane & 15;
    const int kch  = (lane >> 4) * 8;

    // pointwise ownership: one (b, j) element per thread
    const int bl = tid >> 5;            // 0..15
    const int jl = tid & 31;            // 0..31
    const int bg = m0 + bl;
    const int jg = jt * JT_W + jl;

    unsigned int* cnt_g = cnt + bt * 32;   // 128B-spaced group counters

    __shared__ alignas(16) unsigned short h_lds[16 * 520];
    __shared__ alignas(16) unsigned short emb_lds[16 * 328];
    __shared__ int x_lds[16 * TLEN];
    __shared__ float lds_g[4][16][36];

    // ---- persistent weight fragments in VGPRs ----
    const int brow = g0 + (lane & 15);
    short8 whh_r[16], wih_r[10];
#pragma unroll
    for (int kk = 0; kk < 16; ++kk)
        whh_r[kk] = *(const short8*)(whhb + (long)brow * HDIM + kch + kk * 32);
#pragma unroll
    for (int kk = 0; kk < 10; ++kk)
        wih_r[kk] = *(const short8*)(wihb + (long)brow * EPAD + kch + kk * 32);

    // ---- x tokens to LDS (16 rows x 512 steps) ----
    for (int i = tid; i < 16 * TLEN; i += NTHR)
        x_lds[i] = x[(m0 + (i >> 9)) * TLEN + (i & 511)];

    float bsum[4];
#pragma unroll
    for (int g = 0; g < 4; ++g) bsum[g] = b_ih[g * HDIM + jg] + b_hh[g * HDIM + jg];

    float c_reg = c0[bg * HDIM + jg];
    float h_reg = h0[bg * HDIM + jg];
    hb[bg * HDIM + jg] = f2bf(h_reg);   // publish initial h into buffer 0

    __syncthreads();
    if (tid == 0) {
        __builtin_amdgcn_fence(__ATOMIC_RELEASE, "agent");
        __hip_atomic_fetch_add(cnt_g, 1u, __ATOMIC_RELAXED, __HIP_MEMORY_SCOPE_AGENT);
    }

    for (int t = 0; t < TLEN; ++t) {
        // ---- stage emb rows for step t (independent of h: overlaps the wait) ----
        {
            int i0 = tid;
            int row = i0 / 40, cc = i0 - row * 40;
            int tok = x_lds[row * TLEN + t];
            *(short8*)&emb_lds[row * 328 + cc * 8] =
                *(const short8*)(embb + (long)tok * EPAD + cc * 8);
            if (tid < 128) {
                int i1 = tid + NTHR;
                row = i1 / 40; cc = i1 - row * 40;
                tok = x_lds[row * TLEN + t];
                *(short8*)&emb_lds[row * 328 + cc * 8] =
                    *(const short8*)(embb + (long)tok * EPAD + cc * 8);
            }
        }
        // ---- wait for all 16 producers of h(step t) ----
        if (tid == 0) {
            unsigned target = (unsigned)NB_J * (unsigned)(t + 1);
            while (__hip_atomic_load(cnt_g, __ATOMIC_RELAXED, __HIP_MEMORY_SCOPE_AGENT) < target)
                __builtin_amdgcn_s_sleep(1);
        }
        __syncthreads();
        __builtin_amdgcn_fence(__ATOMIC_ACQUIRE, "agent");
        // ---- stage h tile (16 x 512 bf16) ----
        {
            const unsigned short* hread = hb + (t & 1) * (BATCH * HDIM);
            int i0 = tid, i1 = tid + NTHR;
            *(short8*)&h_lds[(i0 >> 6) * 520 + (i0 & 63) * 8] =
                *(const short8*)(hread + (m0 + (i0 >> 6)) * HDIM + (i0 & 63) * 8);
            *(short8*)&h_lds[(i1 >> 6) * 520 + (i1 & 63) * 8] =
                *(const short8*)(hread + (m0 + (i1 >> 6)) * HDIM + (i1 & 63) * 8);
        }
        __syncthreads();
        // ---- MFMA: gates tile = emb @ Wih^T + h @ Whh^T ----
        f32x4 acc_h = {0.f, 0.f, 0.f, 0.f}, acc_e = {0.f, 0.f, 0.f, 0.f};
#pragma unroll
        for (int kk = 0; kk < 16; ++kk) {
            short8 a = *(const short8*)&h_lds[arow * 520 + kch + kk * 32];
            acc_h = __builtin_amdgcn_mfma_f32_16x16x32_bf16(a, whh_r[kk], acc_h, 0, 0, 0);
        }
#pragma unroll
        for (int kk = 0; kk < 10; ++kk) {
            short8 a = *(const short8*)&emb_lds[arow * 328 + kch + kk * 32];
            acc_e = __builtin_amdgcn_mfma_f32_16x16x32_bf16(a, wih_r[kk], acc_e, 0, 0, 0);
        }
        const int crow = (lane >> 4) * 4;
        const int ccol = jsub * 16 + (lane & 15);
#pragma unroll
        for (int r = 0; r < 4; ++r) lds_g[gate][crow + r][ccol] = acc_h[r] + acc_e[r];
        __syncthreads();
        // ---- pointwise LSTM update ----
        float gi = lds_g[0][bl][jl] + bsum[0];
        float gf = lds_g[1][bl][jl] + bsum[1];
        float gg = lds_g[2][bl][jl] + bsum[2];
        float go = lds_g[3][bl][jl] + bsum[3];
        float si = 1.f / (1.f + __expf(-gi));
        float sf = 1.f / (1.f + __expf(-gf));
        float tg = tanhf(gg);
        float so = 1.f / (1.f + __expf(-go));
        c_reg = sf * c_reg + si * tg;
        h_reg = so * tanhf(c_reg);
        unsigned short* hwrite = hb + ((t + 1) & 1) * (BATCH * HDIM);
        hwrite[bg * HDIM + jg] = f2bf(h_reg);
        __syncthreads();
        if (tid == 0) {
            __builtin_amdgcn_fence(__ATOMIC_RELEASE, "agent");
            __hip_atomic_fetch_add(cnt_g, 1u, __ATOMIC_RELAXED, __HIP_MEMORY_SCOPE_AGENT);
        }
    }

    // outputs: [ y(128) | h_out(128x512) | c_out(128x512) ]
    out[BATCH + bg * HDIM + jg] = h_reg;
    out[BATCH + BATCH * HDIM + bg * HDIM + jg] = c_reg;
}

// y[b] = dot(h[b,:], fc_w) + fc_b ; one wave per batch row
__global__ void fc_k(const float* __restrict__ h, const float* __restrict__ fcw,
                     const float* __restrict__ fcb, float* __restrict__ y) {
    int b = blockIdx.x * 4 + (threadIdx.x >> 6);
    int lane = threadIdx.x & 63;
    float s = 0.f;
#pragma unroll
    for (int j = lane; j < HDIM; j += 64) s += h[b * HDIM + j] * fcw[j];
#pragma unroll
    for (int off = 32; off; off >>= 1) s += __shfl_down(s, off, 64);
    if (lane == 0) y[b] = s + fcb[0];
}

extern "C" void kernel_launch(void* const* d_in, const int* in_sizes, int n_in,
                              void* d_out, int out_size, void* d_ws, size_t ws_size,
                              hipStream_t stream) {
    const int*   x   = (const int*)d_in[0];
    const float* h0  = (const float*)d_in[1];
    const float* c0  = (const float*)d_in[2];
    const float* emb = (const float*)d_in[3];
    const float* Wih = (const float*)d_in[4];
    const float* Whh = (const float*)d_in[5];
    const float* bih = (const float*)d_in[6];
    const float* bhh = (const float*)d_in[7];
    const float* fcw = (const float*)d_in[8];
    const float* fcb = (const float*)d_in[9];
    float* out = (float*)d_out;

    char* ws = (char*)d_ws;
    unsigned short* embb = (unsigned short*)(ws);              // 25000*320*2 = 16,000,000
    unsigned short* wihb = (unsigned short*)(ws + 16000000);   //  2048*320*2 =  1,310,720
    unsigned short* whhb = (unsigned short*)(ws + 17310720);   //  2048*512*2 =  2,097,152
    unsigned short* hb   = (unsigned short*)(ws + 19407872);   // 2*128*512*2 =    262,144
    unsigned int*   cnt  = (unsigned int*)(ws + 19670016);     // 8 groups * 128B = 1024
    // total ws use: 19,671,040 bytes

    conv_pad<<<2048, 256, 0, stream>>>(emb, embb, VOCAB, EDIM, EPAD);
    conv_pad<<<512, 256, 0, stream>>>(Wih, wihb, G4, EDIM, EPAD);
    conv_pad<<<512, 256, 0, stream>>>(Whh, whhb, G4, HDIM, HDIM);
    hipMemsetAsync((void*)cnt, 0, 8 * 128, stream);

    void* args[] = {(void*)&x, (void*)&h0, (void*)&c0, (void*)&bih, (void*)&bhh,
                    (void*)&embb, (void*)&wihb, (void*)&whhb, (void*)&hb,
                    (void*)&cnt, (void*)&out};
    hipLaunchCooperativeKernel((void*)lstm_pers, dim3(128), dim3(NTHR), args, 0, stream);

    fc_k<<<32, 256, 0, stream>>>(out + BATCH, fcw, fcb, out);
}

// Round 3
// 1855.357 us; speedup vs baseline: 10.4348x; 3.2807x over previous
//
#include <hip/hip_runtime.h>

#define VOCAB 25000
#define EDIM  300
#define EPAD  320
#define HDIM  512
#define G4    2048
#define BATCH 128
#define TLEN  512
#define NB_J  16    // j-tile blocks per batch group
#define JT_W  32    // j-tile width
#define NTHR  512

typedef __attribute__((ext_vector_type(8))) short short8;
typedef __attribute__((ext_vector_type(4))) float f32x4;

static __device__ __forceinline__ unsigned short f2bf(float f) {
    unsigned int u = __float_as_uint(f);
    unsigned int r = u + 0x7fffu + ((u >> 16) & 1u);   // round-to-nearest-even
    return (unsigned short)(r >> 16);
}

// Convert f32 [rows x cs] -> bf16 [rows x cd], zero-padding cols cs..cd.
__global__ void conv_pad(const float* __restrict__ src, unsigned short* __restrict__ dst,
                         int rows, int cs, int cd) {
    long total = (long)rows * cd;
    for (long i = blockIdx.x * (long)blockDim.x + threadIdx.x; i < total;
         i += (long)gridDim.x * blockDim.x) {
        int r = (int)(i / cd), c = (int)(i % cd);
        dst[i] = (c < cs) ? f2bf(src[(long)r * cs + c]) : (unsigned short)0;
    }
}

// Persistent LSTM. 128 blocks x 512 threads. block = (bt: 16 batch rows) x (jt: 32 h-cols).
// bt = blockIdx&7 so a batch group's 16 blocks share an XCD (perf heuristic only).
// Weights live in NAMED VGPRs (26 short8) for all 512 steps. Cross-block h exchange via
// agent-scope relaxed atomics on hb (coherence-point access) — NO fences, L2 never
// invalidated. Ordering: __syncthreads drains vmcnt before the counter bump.
__global__ __launch_bounds__(NTHR, 2) void lstm_pers(
    const int* __restrict__ x, const float* __restrict__ h0, const float* __restrict__ c0,
    const float* __restrict__ b_ih, const float* __restrict__ b_hh,
    const unsigned short* __restrict__ embb, const unsigned short* __restrict__ wihb,
    const unsigned short* __restrict__ whhb, unsigned short* __restrict__ hb,
    unsigned int* __restrict__ cnt, float* __restrict__ out) {
    const int tid  = threadIdx.x;
    const int bt   = blockIdx.x & 7;    // batch group (XCD-local under i%8 mapping)
    const int jt   = blockIdx.x >> 3;   // 0..15 j tile (32 wide)
    const int m0   = bt * 16;
    const int lane = tid & 63;
    const int wv   = tid >> 6;          // 0..7
    const int gate = wv >> 1, jsub = wv & 1;
    const int g0   = gate * HDIM + jt * JT_W + jsub * 16;
    const int arow = lane & 15;
    const int kch  = (lane >> 4) * 8;

    // pointwise ownership: one (b, j) element per thread
    const int bl = tid >> 5;            // 0..15
    const int jl = tid & 31;            // 0..31
    const int bg = m0 + bl;
    const int jg = jt * JT_W + jl;

    unsigned int* cnt_g = cnt + bt * 32;   // 128B-spaced group counters

    __shared__ alignas(16) unsigned short h_lds[16 * 520];
    __shared__ alignas(16) unsigned short emb_lds[16 * 328];
    __shared__ int x_lds[16 * TLEN];
    __shared__ float lds_g[4][16][36];

    // ---- persistent weight fragments in NAMED registers ----
    const int brow = g0 + (lane & 15);
    const unsigned short* whp = whhb + (long)brow * HDIM + kch;
    const unsigned short* wip = wihb + (long)brow * EPAD + kch;
#define LDH(i) short8 wh##i = *(const short8*)(whp + i * 32);
#define LDE(i) short8 wi##i = *(const short8*)(wip + i * 32);
    LDH(0) LDH(1) LDH(2) LDH(3) LDH(4) LDH(5) LDH(6) LDH(7)
    LDH(8) LDH(9) LDH(10) LDH(11) LDH(12) LDH(13) LDH(14) LDH(15)
    LDE(0) LDE(1) LDE(2) LDE(3) LDE(4) LDE(5) LDE(6) LDE(7) LDE(8) LDE(9)
#undef LDH
#undef LDE

    // ---- x tokens to LDS (16 rows x 512 steps) ----
    for (int i = tid; i < 16 * TLEN; i += NTHR)
        x_lds[i] = x[(m0 + (i >> 9)) * TLEN + (i & 511)];

    float bsum[4];
#pragma unroll
    for (int g = 0; g < 4; ++g) bsum[g] = b_ih[g * HDIM + jg] + b_hh[g * HDIM + jg];

    float c_reg = c0[bg * HDIM + jg];
    float h_reg = h0[bg * HDIM + jg];
    __hip_atomic_store(&hb[bg * HDIM + jg], f2bf(h_reg),
                       __ATOMIC_RELAXED, __HIP_MEMORY_SCOPE_AGENT);

    __syncthreads();   // drains the publish stores (vmcnt 0)
    if (tid == 0)
        __hip_atomic_fetch_add(cnt_g, 1u, __ATOMIC_RELAXED, __HIP_MEMORY_SCOPE_AGENT);

    for (int t = 0; t < TLEN; ++t) {
        // ---- stage emb rows for step t (independent of h: overlaps the wait) ----
        {
            int i0 = tid;
            int row = i0 / 40, cc = i0 - row * 40;
            int tok = x_lds[row * TLEN + t];
            *(short8*)&emb_lds[row * 328 + cc * 8] =
                *(const short8*)(embb + (long)tok * EPAD + cc * 8);
            if (tid < 128) {
                int i1 = tid + NTHR;
                row = i1 / 40; cc = i1 - row * 40;
                tok = x_lds[row * TLEN + t];
                *(short8*)&emb_lds[row * 328 + cc * 8] =
                    *(const short8*)(embb + (long)tok * EPAD + cc * 8);
            }
        }
        // ---- wait for all 16 producers of h(step t) ----
        if (tid == 0) {
            unsigned target = (unsigned)NB_J * (unsigned)(t + 1);
            while (__hip_atomic_load(cnt_g, __ATOMIC_RELAXED, __HIP_MEMORY_SCOPE_AGENT) < target)
                __builtin_amdgcn_s_sleep(1);
        }
        __syncthreads();
        // ---- stage h tile (16 x 512 bf16) via coherent 8B atomic loads ----
        {
            const unsigned long long* hread =
                (const unsigned long long*)(hb + (t & 1) * (BATCH * HDIM));
#pragma unroll
            for (int k = 0; k < 4; ++k) {
                int u = tid + k * NTHR;           // 0..2047
                int row = u >> 7, col8 = u & 127; // 128 ulongs per 512-half row
                unsigned long long v = __hip_atomic_load(
                    hread + (long)(m0 + row) * 128 + col8,
                    __ATOMIC_RELAXED, __HIP_MEMORY_SCOPE_AGENT);
                *(unsigned long long*)&h_lds[row * 520 + col8 * 4] = v;
            }
        }
        __syncthreads();
        // ---- MFMA: gates tile = emb @ Wih^T + h @ Whh^T ----
        f32x4 ah = {0.f, 0.f, 0.f, 0.f}, ae = {0.f, 0.f, 0.f, 0.f};
        short8 a;
#define MH(i) a = *(const short8*)&h_lds[arow * 520 + kch + i * 32]; \
              ah = __builtin_amdgcn_mfma_f32_16x16x32_bf16(a, wh##i, ah, 0, 0, 0);
#define ME(i) a = *(const short8*)&emb_lds[arow * 328 + kch + i * 32]; \
              ae = __builtin_amdgcn_mfma_f32_16x16x32_bf16(a, wi##i, ae, 0, 0, 0);
        MH(0) MH(1) MH(2) MH(3) MH(4) MH(5) MH(6) MH(7)
        MH(8) MH(9) MH(10) MH(11) MH(12) MH(13) MH(14) MH(15)
        ME(0) ME(1) ME(2) ME(3) ME(4) ME(5) ME(6) ME(7) ME(8) ME(9)
#undef MH
#undef ME
        const int crow = (lane >> 4) * 4;
        const int ccol = jsub * 16 + (lane & 15);
#pragma unroll
        for (int r = 0; r < 4; ++r) lds_g[gate][crow + r][ccol] = ah[r] + ae[r];
        __syncthreads();
        // ---- pointwise LSTM update ----
        float gi = lds_g[0][bl][jl] + bsum[0];
        float gf = lds_g[1][bl][jl] + bsum[1];
        float gg = lds_g[2][bl][jl] + bsum[2];
        float go = lds_g[3][bl][jl] + bsum[3];
        float si = 1.f / (1.f + __expf(-gi));
        float sf = 1.f / (1.f + __expf(-gf));
        float tg = tanhf(gg);
        float so = 1.f / (1.f + __expf(-go));
        c_reg = sf * c_reg + si * tg;
        h_reg = so * tanhf(c_reg);
        unsigned short* hwrite = hb + ((t + 1) & 1) * (BATCH * HDIM);
        __hip_atomic_store(&hwrite[bg * HDIM + jg], f2bf(h_reg),
                           __ATOMIC_RELAXED, __HIP_MEMORY_SCOPE_AGENT);
        __syncthreads();   // drains h stores (vmcnt 0) before the counter bump
        if (tid == 0)
            __hip_atomic_fetch_add(cnt_g, 1u, __ATOMIC_RELAXED, __HIP_MEMORY_SCOPE_AGENT);
    }

    // outputs: [ y(128) | h_out(128x512) | c_out(128x512) ]
    out[BATCH + bg * HDIM + jg] = h_reg;
    out[BATCH + BATCH * HDIM + bg * HDIM + jg] = c_reg;
}

// y[b] = dot(h[b,:], fc_w) + fc_b ; one wave per batch row
__global__ void fc_k(const float* __restrict__ h, const float* __restrict__ fcw,
                     const float* __restrict__ fcb, float* __restrict__ y) {
    int b = blockIdx.x * 4 + (threadIdx.x >> 6);
    int lane = threadIdx.x & 63;
    float s = 0.f;
#pragma unroll
    for (int j = lane; j < HDIM; j += 64) s += h[b * HDIM + j] * fcw[j];
#pragma unroll
    for (int off = 32; off; off >>= 1) s += __shfl_down(s, off, 64);
    if (lane == 0) y[b] = s + fcb[0];
}

extern "C" void kernel_launch(void* const* d_in, const int* in_sizes, int n_in,
                              void* d_out, int out_size, void* d_ws, size_t ws_size,
                              hipStream_t stream) {
    const int*   x   = (const int*)d_in[0];
    const float* h0  = (const float*)d_in[1];
    const float* c0  = (const float*)d_in[2];
    const float* emb = (const float*)d_in[3];
    const float* Wih = (const float*)d_in[4];
    const float* Whh = (const float*)d_in[5];
    const float* bih = (const float*)d_in[6];
    const float* bhh = (const float*)d_in[7];
    const float* fcw = (const float*)d_in[8];
    const float* fcb = (const float*)d_in[9];
    float* out = (float*)d_out;

    char* ws = (char*)d_ws;
    unsigned short* embb = (unsigned short*)(ws);              // 25000*320*2 = 16,000,000
    unsigned short* wihb = (unsigned short*)(ws + 16000000);   //  2048*320*2 =  1,310,720
    unsigned short* whhb = (unsigned short*)(ws + 17310720);   //  2048*512*2 =  2,097,152
    unsigned short* hb   = (unsigned short*)(ws + 19407872);   // 2*128*512*2 =    262,144
    unsigned int*   cnt  = (unsigned int*)(ws + 19670016);     // 8 groups * 128B = 1024
    // total ws use: 19,671,040 bytes

    conv_pad<<<2048, 256, 0, stream>>>(emb, embb, VOCAB, EDIM, EPAD);
    conv_pad<<<512, 256, 0, stream>>>(Wih, wihb, G4, EDIM, EPAD);
    conv_pad<<<512, 256, 0, stream>>>(Whh, whhb, G4, HDIM, HDIM);
    hipMemsetAsync((void*)cnt, 0, 8 * 128, stream);

    void* args[] = {(void*)&x, (void*)&h0, (void*)&c0, (void*)&bih, (void*)&bhh,
                    (void*)&embb, (void*)&wihb, (void*)&whhb, (void*)&hb,
                    (void*)&cnt, (void*)&out};
    hipLaunchCooperativeKernel((void*)lstm_pers, dim3(128), dim3(NTHR), args, 0, stream);

    fc_k<<<32, 256, 0, stream>>>(out + BATCH, fcw, fcb, out);
}

// Round 4
// 1606.673 us; speedup vs baseline: 12.0499x; 1.1548x over previous
//
#include <hip/hip_runtime.h>

#define VOCAB 25000
#define EDIM  300
#define EPAD  320
#define HDIM  512
#define BATCH 128
#define TLEN  512
#define NTHR  512

typedef __attribute__((ext_vector_type(8))) short short8;
typedef __attribute__((ext_vector_type(4))) float f32x4;
typedef unsigned int u32;
typedef unsigned long long u64;

static __device__ __forceinline__ unsigned short f2bf(float f) {
    unsigned int u = __float_as_uint(f);
    unsigned int r = u + 0x7fffu + ((u >> 16) & 1u);   // round-to-nearest-even
    return (unsigned short)(r >> 16);
}

// row-per-block f32 -> bf16 pad convert (no int div in inner loop)
__global__ void conv_pad_row(const float* __restrict__ src, unsigned short* __restrict__ dst,
                             int rows, int cs, int cd) {
    for (int r = blockIdx.x; r < rows; r += gridDim.x)
        for (int c = threadIdx.x; c < cd; c += blockDim.x)
            dst[(long)r * cd + c] = (c < cs) ? f2bf(src[(long)r * cs + c]) : (unsigned short)0;
}

// Persistent LSTM. 128 blocks x 512 threads. block = (bt: 16 batch rows) x (jt: 32 h-cols).
// Weights in 26 named short8 regs. Cross-block h exchange: TAGGED dwords
// (tag<<16 | bf16) in double-buffered hb, relaxed agent atomics, per-thread
// tag-check + retry — no counter, no fences, one round trip per step.
// LDS: XOR chunk swizzle (chunk ^ row&7) on h_lds/emb_lds -> conflict-free b128 reads.
__global__ __launch_bounds__(NTHR, 2) void lstm_pers(
    const int* __restrict__ x, const float* __restrict__ h0, const float* __restrict__ c0,
    const float* __restrict__ b_ih, const float* __restrict__ b_hh,
    const unsigned short* __restrict__ embb, const unsigned short* __restrict__ wihb,
    const unsigned short* __restrict__ whhb, u32* __restrict__ hb, float* __restrict__ out) {
    const int tid  = threadIdx.x;
    const int bt   = blockIdx.x & 7;    // batch group (XCD-local under i%8 mapping)
    const int jt   = blockIdx.x >> 3;   // 0..15 j tile (32 wide)
    const int m0   = bt * 16;
    const int lane = tid & 63;
    const int wv   = tid >> 6;          // 0..7
    const int gate = wv >> 1, jsub = wv & 1;
    const int g0   = gate * HDIM + jt * 32 + jsub * 16;
    const int r    = lane & 15;         // A row / B col
    const int q    = lane >> 4;         // k quarter
    const int sw   = r & 7;             // LDS swizzle key

    const int bl = tid >> 5, jl = tid & 31;     // pointwise ownership
    const int bg = m0 + bl, jg = jt * 32 + jl;

    __shared__ alignas(16) unsigned short h_lds[16 * 512];
    __shared__ alignas(16) unsigned short emb_lds[2][16 * 320];
    __shared__ int x_lds[16 * TLEN];
    __shared__ float lds_g[4][16][36];

    // ---- persistent weight fragments in NAMED registers ----
    const int brow = g0 + r;
    const unsigned short* whp = whhb + (long)brow * HDIM + q * 8;
    const unsigned short* wip = wihb + (long)brow * EPAD + q * 8;
#define LDH(i) short8 wh##i = *(const short8*)(whp + i * 32);
#define LDE(i) short8 wi##i = *(const short8*)(wip + i * 32);
    LDH(0) LDH(1) LDH(2) LDH(3) LDH(4) LDH(5) LDH(6) LDH(7)
    LDH(8) LDH(9) LDH(10) LDH(11) LDH(12) LDH(13) LDH(14) LDH(15)
    LDE(0) LDE(1) LDE(2) LDE(3) LDE(4) LDE(5) LDE(6) LDE(7) LDE(8) LDE(9)
#undef LDH
#undef LDE

    // ---- x tokens to LDS ----
    for (int i = tid; i < 16 * TLEN; i += NTHR)
        x_lds[i] = x[(m0 + (i >> 9)) * TLEN + (i & 511)];

    const float bsum0 = b_ih[0 * HDIM + jg] + b_hh[0 * HDIM + jg];
    const float bsum1 = b_ih[1 * HDIM + jg] + b_hh[1 * HDIM + jg];
    const float bsum2 = b_ih[2 * HDIM + jg] + b_hh[2 * HDIM + jg];
    const float bsum3 = b_ih[3 * HDIM + jg] + b_hh[3 * HDIM + jg];

    float c_reg = c0[bg * HDIM + jg];
    float h_reg = h0[bg * HDIM + jg];

    u32* const hb0 = hb;
    u32* const hb1 = hb + BATCH * HDIM;
    // publish tagged h0 (tag 0) into buffer 0
    __hip_atomic_store(hb0 + bg * HDIM + jg, (u32)f2bf(h_reg),
                       __ATOMIC_RELAXED, __HIP_MEMORY_SCOPE_AGENT);

    // ---- precomputed staging offsets (8 x 8B units per thread) ----
    u32 hoff[8], lofs[8];
#pragma unroll
    for (int k = 0; k < 8; ++k) {
        int u   = tid + k * NTHR;       // 0..4095
        int row = u >> 8, col = u & 255;              // 256 dwords per 512-col row
        hoff[k] = (u32)((m0 + row) * 256 + col);      // u64 units in hb
        int chunk = col >> 2, sub = col & 3;
        lofs[k] = (u32)(row * 512 + ((chunk ^ (row & 7)) * 4 + sub) * 2);   // shorts
    }

    __syncthreads();   // x_lds ready
    // ---- stage emb for t=0 into buffer 0 ----
    {
        int row = tid / 40, cc = tid - row * 40;
        int tok = x_lds[row * TLEN];
        *(short8*)&emb_lds[0][row * 320 + ((cc ^ (row & 7)) * 8)] =
            *(const short8*)(embb + (long)tok * EPAD + cc * 8);
        if (tid < 128) {
            int i1 = tid + NTHR; int row2 = i1 / 40, cc2 = i1 - row2 * 40;
            int tok2 = x_lds[row2 * TLEN];
            *(short8*)&emb_lds[0][row2 * 320 + ((cc2 ^ (row2 & 7)) * 8)] =
                *(const short8*)(embb + (long)tok2 * EPAD + cc2 * 8);
        }
    }
    __syncthreads();

    for (int t = 0; t < TLEN; ++t) {
        const int pb = t & 1;
        const u64* hsrc = (const u64*)(pb ? hb1 : hb0);
        // 1. issue h tagged loads early (latency hides under emb prefetch + emb MFMAs)
        u64 hv[8];
#pragma unroll
        for (int k = 0; k < 8; ++k)
            hv[k] = __hip_atomic_load(hsrc + hoff[k], __ATOMIC_RELAXED, __HIP_MEMORY_SCOPE_AGENT);

        // 2. prefetch emb rows for t+1 into the other buffer
        {
            int tn = (t + 1 < TLEN) ? (t + 1) : (TLEN - 1);
            unsigned short* ebuf = (unsigned short*)emb_lds[pb ^ 1];
            int row = tid / 40, cc = tid - row * 40;
            int tok = x_lds[row * TLEN + tn];
            *(short8*)&ebuf[row * 320 + ((cc ^ (row & 7)) * 8)] =
                *(const short8*)(embb + (long)tok * EPAD + cc * 8);
            if (tid < 128) {
                int i1 = tid + NTHR; int row2 = i1 / 40, cc2 = i1 - row2 * 40;
                int tok2 = x_lds[row2 * TLEN + tn];
                *(short8*)&ebuf[row2 * 320 + ((cc2 ^ (row2 & 7)) * 8)] =
                    *(const short8*)(embb + (long)tok2 * EPAD + cc2 * 8);
            }
        }

        // 3. emb MFMAs from current buffer (independent of h)
        const unsigned short* ecur = (const unsigned short*)emb_lds[pb];
        f32x4 ae = {0.f, 0.f, 0.f, 0.f};
        short8 a;
#define ME(i) a = *(const short8*)&ecur[r * 320 + (((q + 4 * i) ^ sw) * 8)]; \
              ae = __builtin_amdgcn_mfma_f32_16x16x32_bf16(a, wi##i, ae, 0, 0, 0);
        ME(0) ME(1) ME(2) ME(3) ME(4) ME(5) ME(6) ME(7) ME(8) ME(9)
#undef ME

        // 4. verify tags, retry stale
        const u32 want = (u32)t;
        while (1) {
            u32 bad = 0;
#pragma unroll
            for (int k = 0; k < 8; ++k)
                bad |= (((u32)(hv[k] >> 16) & 0xFFFFu) ^ want) | (((u32)(hv[k] >> 48)) ^ want);
            if (!bad) break;
#pragma unroll
            for (int k = 0; k < 8; ++k)
                hv[k] = __hip_atomic_load(hsrc + hoff[k], __ATOMIC_RELAXED, __HIP_MEMORY_SCOPE_AGENT);
        }

        // 5. strip tags -> h_lds (swizzled, conflict-free b32 writes)
#pragma unroll
        for (int k = 0; k < 8; ++k) {
            u32 two = ((u32)hv[k] & 0xFFFFu) | (((u32)(hv[k] >> 32) & 0xFFFFu) << 16);
            *(u32*)&h_lds[lofs[k]] = two;
        }
        __syncthreads();

        // 6. recurrent MFMAs
        f32x4 ah = {0.f, 0.f, 0.f, 0.f};
#define MH(i) a = *(const short8*)&h_lds[r * 512 + (((q + 4 * i) ^ sw) * 8)]; \
              ah = __builtin_amdgcn_mfma_f32_16x16x32_bf16(a, wh##i, ah, 0, 0, 0);
        MH(0) MH(1) MH(2) MH(3) MH(4) MH(5) MH(6) MH(7)
        MH(8) MH(9) MH(10) MH(11) MH(12) MH(13) MH(14) MH(15)
#undef MH

        const int crow = q * 4;
        const int ccol = jsub * 16 + r;
#pragma unroll
        for (int rr = 0; rr < 4; ++rr) lds_g[gate][crow + rr][ccol] = ah[rr] + ae[rr];
        __syncthreads();

        // 7. pointwise LSTM update
        float gi = lds_g[0][bl][jl] + bsum0;
        float gf = lds_g[1][bl][jl] + bsum1;
        float gg = lds_g[2][bl][jl] + bsum2;
        float go = lds_g[3][bl][jl] + bsum3;
        float si = 1.f / (1.f + __expf(-gi));
        float sf = 1.f / (1.f + __expf(-gf));
        float tg = 2.f / (1.f + __expf(-2.f * gg)) - 1.f;
        float so = 1.f / (1.f + __expf(-go));
        c_reg = sf * c_reg + si * tg;
        float th = 2.f / (1.f + __expf(-2.f * c_reg)) - 1.f;
        h_reg = so * th;
        u32* dst = (pb ? hb0 : hb1) + bg * HDIM + jg;
        __hip_atomic_store(dst, ((u32)(t + 1) << 16) | (u32)f2bf(h_reg),
                           __ATOMIC_RELAXED, __HIP_MEMORY_SCOPE_AGENT);
        __syncthreads();   // protects h_lds / lds_g / emb_lds[pb^1] for next iter
    }

    // outputs: [ y(128) | h_out(128x512) | c_out(128x512) ]
    out[BATCH + bg * HDIM + jg] = h_reg;
    out[BATCH + BATCH * HDIM + bg * HDIM + jg] = c_reg;
}

// y[b] = dot(h[b,:], fc_w) + fc_b ; one wave per batch row
__global__ void fc_k(const float* __restrict__ h, const float* __restrict__ fcw,
                     const float* __restrict__ fcb, float* __restrict__ y) {
    int b = blockIdx.x * 4 + (threadIdx.x >> 6);
    int lane = threadIdx.x & 63;
    float s = 0.f;
#pragma unroll
    for (int j = lane; j < HDIM; j += 64) s += h[b * HDIM + j] * fcw[j];
#pragma unroll
    for (int off = 32; off; off >>= 1) s += __shfl_down(s, off, 64);
    if (lane == 0) y[b] = s + fcb[0];
}

extern "C" void kernel_launch(void* const* d_in, const int* in_sizes, int n_in,
                              void* d_out, int out_size, void* d_ws, size_t ws_size,
                              hipStream_t stream) {
    const int*   x   = (const int*)d_in[0];
    const float* h0  = (const float*)d_in[1];
    const float* c0  = (const float*)d_in[2];
    const float* emb = (const float*)d_in[3];
    const float* Wih = (const float*)d_in[4];
    const float* Whh = (const float*)d_in[5];
    const float* bih = (const float*)d_in[6];
    const float* bhh = (const float*)d_in[7];
    const float* fcw = (const float*)d_in[8];
    const float* fcb = (const float*)d_in[9];
    float* out = (float*)d_out;

    char* ws = (char*)d_ws;
    unsigned short* embb = (unsigned short*)(ws);              // 25000*320*2 = 16,000,000
    unsigned short* wihb = (unsigned short*)(ws + 16000000);   //  2048*320*2 =  1,310,720
    unsigned short* whhb = (unsigned short*)(ws + 17310720);   //  2048*512*2 =  2,097,152
    u32*            hb   = (u32*)(ws + 19407872);              // 2*128*512*4 =    524,288
    // total ws use: 19,932,160 bytes

    conv_pad_row<<<4096, 256, 0, stream>>>(emb, embb, VOCAB, EDIM, EPAD);
    conv_pad_row<<<2048, 256, 0, stream>>>(Wih, wihb, 4 * HDIM, EDIM, EPAD);
    conv_pad_row<<<2048, 256, 0, stream>>>(Whh, whhb, 4 * HDIM, HDIM, HDIM);

    void* args[] = {(void*)&x, (void*)&h0, (void*)&c0, (void*)&bih, (void*)&bhh,
                    (void*)&embb, (void*)&wihb, (void*)&whhb, (void*)&hb, (void*)&out};
    hipLaunchCooperativeKernel((void*)lstm_pers, dim3(128), dim3(NTHR), args, 0, stream);

    fc_k<<<32, 256, 0, stream>>>(out + BATCH, fcw, fcb, out);
}

// Round 5
// 1495.021 us; speedup vs baseline: 12.9498x; 1.0747x over previous
//
#include <hip/hip_runtime.h>

#define VOCAB 25000
#define EDIM  300
#define EPAD  320
#define HDIM  512
#define BATCH 128
#define TLEN  512
#define NTHR  512

typedef __attribute__((ext_vector_type(8))) short short8;
typedef __attribute__((ext_vector_type(4))) float f32x4;
typedef unsigned int u32;
typedef unsigned long long u64;

// LDS-only barrier: does NOT drain vmcnt — global stores/loads stay in flight.
#define BAR_LDS() do {                                        \
    asm volatile("s_waitcnt lgkmcnt(0)" ::: "memory");        \
    __builtin_amdgcn_sched_barrier(0);                        \
    __builtin_amdgcn_s_barrier();                             \
    __builtin_amdgcn_sched_barrier(0);                        \
} while (0)

static __device__ __forceinline__ unsigned short f2bf(float f) {
    unsigned int u = __float_as_uint(f);
    unsigned int r = u + 0x7fffu + ((u >> 16) & 1u);   // round-to-nearest-even
    return (unsigned short)(r >> 16);
}

// row-per-block f32 -> bf16 pad convert
__global__ void conv_pad_row(const float* __restrict__ src, unsigned short* __restrict__ dst,
                             int rows, int cs, int cd) {
    for (int r = blockIdx.x; r < rows; r += gridDim.x)
        for (int c = threadIdx.x; c < cd; c += blockDim.x)
            dst[(long)r * cd + c] = (c < cs) ? f2bf(src[(long)r * cs + c]) : (unsigned short)0;
}

// Persistent LSTM. 128 blocks x 512 threads. block = (bt: 16 batch rows) x (jt: 32 h-cols).
// Weights in 26 named short8 regs. Cross-block h exchange: TAGGED dwords (tag<<16|bf16)
// in double-buffered hb, relaxed agent atomics + per-thread tag retry. In-loop barriers
// are LDS-only (no vmcnt drain) so the MALL store-ack and emb prefetch latency stay off
// the serial path. h-MFMA uses 4 independent accumulator chains.
__global__ __launch_bounds__(NTHR, 2) void lstm_pers(
    const int* __restrict__ x, const float* __restrict__ h0, const float* __restrict__ c0,
    const float* __restrict__ b_ih, const float* __restrict__ b_hh,
    const unsigned short* __restrict__ embb, const unsigned short* __restrict__ wihb,
    const unsigned short* __restrict__ whhb, u32* __restrict__ hb, float* __restrict__ out) {
    const int tid  = threadIdx.x;
    const int bt   = blockIdx.x & 7;    // batch group (XCD-local under i%8 mapping)
    const int jt   = blockIdx.x >> 3;   // 0..15 j tile (32 wide)
    const int m0   = bt * 16;
    const int lane = tid & 63;
    const int wv   = tid >> 6;          // 0..7
    const int gate = wv >> 1, jsub = wv & 1;
    const int g0   = gate * HDIM + jt * 32 + jsub * 16;
    const int r    = lane & 15;         // A row / B col
    const int q    = lane >> 4;         // k quarter
    const int sw   = r & 7;             // LDS swizzle key

    const int bl = tid >> 5, jl = tid & 31;     // pointwise ownership
    const int bg = m0 + bl, jg = jt * 32 + jl;

    __shared__ alignas(16) unsigned short h_lds[16 * 512];
    __shared__ alignas(16) unsigned short emb_lds[2][16 * 320];
    __shared__ int x_lds[16 * TLEN];
    __shared__ float lds_g[4][16][36];

    // ---- persistent weight fragments in NAMED registers ----
    const int brow = g0 + r;
    const unsigned short* whp = whhb + (long)brow * HDIM + q * 8;
    const unsigned short* wip = wihb + (long)brow * EPAD + q * 8;
#define LDH(i) short8 wh##i = *(const short8*)(whp + i * 32);
#define LDE(i) short8 wi##i = *(const short8*)(wip + i * 32);
    LDH(0) LDH(1) LDH(2) LDH(3) LDH(4) LDH(5) LDH(6) LDH(7)
    LDH(8) LDH(9) LDH(10) LDH(11) LDH(12) LDH(13) LDH(14) LDH(15)
    LDE(0) LDE(1) LDE(2) LDE(3) LDE(4) LDE(5) LDE(6) LDE(7) LDE(8) LDE(9)
#undef LDH
#undef LDE

    // ---- x tokens to LDS ----
    for (int i = tid; i < 16 * TLEN; i += NTHR)
        x_lds[i] = x[(m0 + (i >> 9)) * TLEN + (i & 511)];

    const float bsum0 = b_ih[0 * HDIM + jg] + b_hh[0 * HDIM + jg];
    const float bsum1 = b_ih[1 * HDIM + jg] + b_hh[1 * HDIM + jg];
    const float bsum2 = b_ih[2 * HDIM + jg] + b_hh[2 * HDIM + jg];
    const float bsum3 = b_ih[3 * HDIM + jg] + b_hh[3 * HDIM + jg];

    float c_reg = c0[bg * HDIM + jg];
    float h_reg = h0[bg * HDIM + jg];

    u32* const hb0 = hb;
    u32* const hb1 = hb + BATCH * HDIM;
    // publish tagged h0 (tag 0) into buffer 0
    __hip_atomic_store(hb0 + bg * HDIM + jg, (u32)f2bf(h_reg),
                       __ATOMIC_RELAXED, __HIP_MEMORY_SCOPE_AGENT);

    // ---- precomputed staging offsets (8 x 8B units per thread) ----
    u32 hoff[8], lofs[8];
#pragma unroll
    for (int k = 0; k < 8; ++k) {
        int u   = tid + k * NTHR;       // 0..4095
        int row = u >> 8, col = u & 255;              // 256 u64 per 512-col row
        hoff[k] = (u32)((m0 + row) * 256 + col);      // u64 units in hb
        int chunk = col >> 2, sub = col & 3;
        lofs[k] = (u32)(row * 512 + ((chunk ^ (row & 7)) * 4 + sub) * 2);   // shorts
    }

    // emb staging slots: slot0 = tid (0..511), slot1 = 512 + (tid&127) (redundant for tid>=128)
    const int row0 = tid / 40,            cc0 = tid - row0 * 40;
    const int i1   = NTHR + (tid & 127);
    const int row1 = i1 / 40,             cc1 = i1 - row1 * 40;

    __syncthreads();   // x_lds ready
    // ---- stage emb for t=0 into buffer 0 ----
    {
        int tok0 = x_lds[row0 * TLEN];
        *(short8*)&emb_lds[0][row0 * 320 + ((cc0 ^ (row0 & 7)) * 8)] =
            *(const short8*)(embb + (long)tok0 * EPAD + cc0 * 8);
        if (tid < 128) {
            int tok1 = x_lds[row1 * TLEN];
            *(short8*)&emb_lds[0][row1 * 320 + ((cc1 ^ (row1 & 7)) * 8)] =
                *(const short8*)(embb + (long)tok1 * EPAD + cc1 * 8);
        }
    }
    __syncthreads();

    for (int t = 0; t < TLEN; ++t) {
        const int pb = t & 1;
        const u64* hsrc = (const u64*)(pb ? hb1 : hb0);
        // 1. issue h tagged loads first (oldest in vm queue -> precise vmcnt wait)
        u64 hv[8];
#pragma unroll
        for (int k = 0; k < 8; ++k)
            hv[k] = __hip_atomic_load(hsrc + hoff[k], __ATOMIC_RELAXED, __HIP_MEMORY_SCOPE_AGENT);

        // 2. issue emb global loads for t+1 into registers (uniform control flow)
        const int tn = (t + 1 < TLEN) ? (t + 1) : (TLEN - 1);
        short8 ev0 = *(const short8*)(embb + (long)x_lds[row0 * TLEN + tn] * EPAD + cc0 * 8);
        short8 ev1 = *(const short8*)(embb + (long)x_lds[row1 * TLEN + tn] * EPAD + cc1 * 8);
        __builtin_amdgcn_sched_barrier(0);

        // 3. emb MFMAs on current buffer (LDS-only, no vm dependency)
        const unsigned short* ecur = (const unsigned short*)emb_lds[pb];
        f32x4 ae0 = {0.f, 0.f, 0.f, 0.f}, ae1 = {0.f, 0.f, 0.f, 0.f};
        {
            short8 a;
#define ME(i, A) a = *(const short8*)&ecur[r * 320 + (((q + 4 * i) ^ sw) * 8)]; \
                 A = __builtin_amdgcn_mfma_f32_16x16x32_bf16(a, wi##i, A, 0, 0, 0);
            ME(0, ae0) ME(1, ae1) ME(2, ae0) ME(3, ae1) ME(4, ae0)
            ME(5, ae1) ME(6, ae0) ME(7, ae1) ME(8, ae0) ME(9, ae1)
#undef ME
        }
        __builtin_amdgcn_sched_barrier(0);

        // 4. verify tags, retry stale (waits only on hv: vmcnt(2))
        const u32 want = (u32)t;
        while (1) {
            u32 bad = 0;
#pragma unroll
            for (int k = 0; k < 8; ++k)
                bad |= (((u32)(hv[k] >> 16) & 0xFFFFu) ^ want) | (((u32)(hv[k] >> 48)) ^ want);
            if (!bad) break;
#pragma unroll
            for (int k = 0; k < 8; ++k)
                hv[k] = __hip_atomic_load(hsrc + hoff[k], __ATOMIC_RELAXED, __HIP_MEMORY_SCOPE_AGENT);
        }

        // 5. strip tags -> h_lds (swizzled, conflict-free b32 writes)
#pragma unroll
        for (int k = 0; k < 8; ++k) {
            u32 two = ((u32)hv[k] & 0xFFFFu) | (((u32)(hv[k] >> 32) & 0xFFFFu) << 16);
            *(u32*)&h_lds[lofs[k]] = two;
        }
        BAR_LDS();

        // 6. recurrent MFMAs, 4 independent chains
        f32x4 ah0 = {0.f, 0.f, 0.f, 0.f}, ah1 = {0.f, 0.f, 0.f, 0.f};
        f32x4 ah2 = {0.f, 0.f, 0.f, 0.f}, ah3 = {0.f, 0.f, 0.f, 0.f};
        {
            short8 a;
#define MH(i, A) a = *(const short8*)&h_lds[r * 512 + (((q + 4 * i) ^ sw) * 8)]; \
                 A = __builtin_amdgcn_mfma_f32_16x16x32_bf16(a, wh##i, A, 0, 0, 0);
            MH(0, ah0) MH(1, ah1) MH(2, ah2) MH(3, ah3)
            MH(4, ah0) MH(5, ah1) MH(6, ah2) MH(7, ah3)
            MH(8, ah0) MH(9, ah1) MH(10, ah2) MH(11, ah3)
            MH(12, ah0) MH(13, ah1) MH(14, ah2) MH(15, ah3)
#undef MH
        }
        __builtin_amdgcn_sched_barrier(0);

        // 6b. deferred emb LDS writes for t+1 (global data arrived during the wait)
        {
            unsigned short* ebuf = (unsigned short*)emb_lds[pb ^ 1];
            *(short8*)&ebuf[row0 * 320 + ((cc0 ^ (row0 & 7)) * 8)] = ev0;
            if (tid < 128)
                *(short8*)&ebuf[row1 * 320 + ((cc1 ^ (row1 & 7)) * 8)] = ev1;
        }

        // 6c. gate tile -> lds_g
        f32x4 s = (ah0 + ah1) + (ah2 + ah3) + (ae0 + ae1);
        const int crow = q * 4;
        const int ccol = jsub * 16 + r;
#pragma unroll
        for (int rr = 0; rr < 4; ++rr) lds_g[gate][crow + rr][ccol] = s[rr];
        BAR_LDS();

        // 7. pointwise LSTM update
        float gi = lds_g[0][bl][jl] + bsum0;
        float gf = lds_g[1][bl][jl] + bsum1;
        float gg = lds_g[2][bl][jl] + bsum2;
        float go = lds_g[3][bl][jl] + bsum3;
        float si = 1.f / (1.f + __expf(-gi));
        float sf = 1.f / (1.f + __expf(-gf));
        float tg = 2.f / (1.f + __expf(-2.f * gg)) - 1.f;
        float so = 1.f / (1.f + __expf(-go));
        c_reg = sf * c_reg + si * tg;
        float th = 2.f / (1.f + __expf(-2.f * c_reg)) - 1.f;
        h_reg = so * th;
        u32* dst = (pb ? hb0 : hb1) + bg * HDIM + jg;
        __hip_atomic_store(dst, ((u32)(t + 1) << 16) | (u32)f2bf(h_reg),
                           __ATOMIC_RELAXED, __HIP_MEMORY_SCOPE_AGENT);
        BAR_LDS();   // LDS-only: the store drains in background
    }

    // outputs: [ y(128) | h_out(128x512) | c_out(128x512) ]
    out[BATCH + bg * HDIM + jg] = h_reg;
    out[BATCH + BATCH * HDIM + bg * HDIM + jg] = c_reg;
}

// y[b] = dot(h[b,:], fc_w) + fc_b ; one wave per batch row
__global__ void fc_k(const float* __restrict__ h, const float* __restrict__ fcw,
                     const float* __restrict__ fcb, float* __restrict__ y) {
    int b = blockIdx.x * 4 + (threadIdx.x >> 6);
    int lane = threadIdx.x & 63;
    float s = 0.f;
#pragma unroll
    for (int j = lane; j < HDIM; j += 64) s += h[b * HDIM + j] * fcw[j];
#pragma unroll
    for (int off = 32; off; off >>= 1) s += __shfl_down(s, off, 64);
    if (lane == 0) y[b] = s + fcb[0];
}

extern "C" void kernel_launch(void* const* d_in, const int* in_sizes, int n_in,
                              void* d_out, int out_size, void* d_ws, size_t ws_size,
                              hipStream_t stream) {
    const int*   x   = (const int*)d_in[0];
    const float* h0  = (const float*)d_in[1];
    const float* c0  = (const float*)d_in[2];
    const float* emb = (const float*)d_in[3];
    const float* Wih = (const float*)d_in[4];
    const float* Whh = (const float*)d_in[5];
    const float* bih = (const float*)d_in[6];
    const float* bhh = (const float*)d_in[7];
    const float* fcw = (const float*)d_in[8];
    const float* fcb = (const float*)d_in[9];
    float* out = (float*)d_out;

    char* ws = (char*)d_ws;
    unsigned short* embb = (unsigned short*)(ws);              // 25000*320*2 = 16,000,000
    unsigned short* wihb = (unsigned short*)(ws + 16000000);   //  2048*320*2 =  1,310,720
    unsigned short* whhb = (unsigned short*)(ws + 17310720);   //  2048*512*2 =  2,097,152
    u32*            hb   = (u32*)(ws + 19407872);              // 2*128*512*4 =    524,288
    // total ws use: 19,932,160 bytes

    conv_pad_row<<<4096, 256, 0, stream>>>(emb, embb, VOCAB, EDIM, EPAD);
    conv_pad_row<<<2048, 256, 0, stream>>>(Wih, wihb, 4 * HDIM, EDIM, EPAD);
    conv_pad_row<<<2048, 256, 0, stream>>>(Whh, whhb, 4 * HDIM, HDIM, HDIM);

    void* args[] = {(void*)&x, (void*)&h0, (void*)&c0, (void*)&bih, (void*)&bhh,
                    (void*)&embb, (void*)&wihb, (void*)&whhb, (void*)&hb, (void*)&out};
    hipLaunchCooperativeKernel((void*)lstm_pers, dim3(128), dim3(NTHR), args, 0, stream);

    fc_k<<<32, 256, 0, stream>>>(out + BATCH, fcw, fcb, out);
}